// Round 4
// baseline (541.628 us; speedup 1.0000x reference)
//
#include <hip/hip_runtime.h>

// AR(16) sequence generation, out (B=4096, T=8192) fp32.
// Time-segmented with zero-state warmup (contractive: |roots|>=1.1 => decay
// 0.909/step; 0.909^96 ~ 1e-4 << 0.48 threshold).
// R4 (2nd resubmit; R2/R3 benches failed at GPU acquisition):
//   rolling in-place prefetch + non-temporal output stores.
//   - R3 measured: 32 VGPR, occ 59%, VALUBusy 20.6%, 2.17 TB/s, 158 us.
//     Latency-bound: without prefetch, each chunk's compute waits vmcnt
//     through the previous chunk's 64-line scattered stores + its own 16
//     load misses (~2000+ cy stall vs 512 cy compute).
//   - Rolling prefetch: at step k consume buf[k], then immediately load next
//     chunk's element into buf[k]. Pipelining of R2's double-buffer at ZERO
//     extra registers -> stays in the <=64 VGPR / 8 blocks/CU band.
//   - Non-temporal stores: out (134 MB, write-once) must not evict noise
//     (134 MB, read ~2.5x due to warmup) from the 256 MB L3.

#define SEG_L 64    // output-producing steps per segment
#define SEG_W 96    // max zero-state warmup steps (s>=2)

typedef float f32x4 __attribute__((ext_vector_type(4)));

// Force a uniform value into an SGPR (frees a VGPR; v_fma takes 1 SGPR src).
__device__ __forceinline__ float sload(float v) {
    return __uint_as_float(__builtin_amdgcn_readfirstlane(__float_as_uint(v)));
}

// One recurrence step. Window invariant: at rotation k, y[t-16+i] == w[(k+i)&15].
// Dependent terms (i=14,15 -> produced 2 and 1 steps ago) applied LAST so the
// per-step critical path is ~2 FMA latencies; the rest is a 4-way tree.
__device__ __forceinline__ float arstep(const float (&c)[16], const float (&w)[16],
                                        int k, float e) {
    float p0 = fmaf(c[0],  w[(k + 0)  & 15], e);
    float p1 =      c[1] * w[(k + 1)  & 15];
    float p2 =      c[2] * w[(k + 2)  & 15];
    float p3 =      c[3] * w[(k + 3)  & 15];
    p0 = fmaf(c[4],  w[(k + 4)  & 15], p0);
    p1 = fmaf(c[5],  w[(k + 5)  & 15], p1);
    p2 = fmaf(c[6],  w[(k + 6)  & 15], p2);
    p3 = fmaf(c[7],  w[(k + 7)  & 15], p3);
    p0 = fmaf(c[8],  w[(k + 8)  & 15], p0);
    p1 = fmaf(c[9],  w[(k + 9)  & 15], p1);
    p2 = fmaf(c[10], w[(k + 10) & 15], p2);
    p3 = fmaf(c[11], w[(k + 11) & 15], p3);
    p0 = fmaf(c[12], w[(k + 12) & 15], p0);
    p1 = fmaf(c[13], w[(k + 13) & 15], p1);
    p0 += p2;
    p1 += p3;
    p0 += p1;
    p0 = fmaf(c[14], w[(k + 14) & 15], p0);   // critical-path tail
    return fmaf(c[15], w[(k + 15) & 15], p0); // newest value last
}

__global__ __launch_bounds__(256, 8)   // 8 waves/EU => <=64 VGPR => 32 waves/CU
void ARModel_27925877359180_kernel(const float* __restrict__ init,   // (B,16)
                                   const float* __restrict__ coeff,  // (16)
                                   const float* __restrict__ lns,    // (1)
                                   const float* __restrict__ noise,  // (TN,B)
                                   float* __restrict__ out,          // (B,T)
                                   int B, int TN, int T, int nbc)
{
    const int blk = blockIdx.x;
    const int s   = blk / nbc;                       // segment index
    const int b   = (blk % nbc) * blockDim.x + threadIdx.x;
    if (b >= B) return;

    float c[16];
#pragma unroll
    for (int i = 0; i < 16; ++i) c[i] = sload(coeff[i]);
    const float nstd = sload(expf(lns[0]));

    const int  start  = s * SEG_L;                   // first main noise index
    const int  len    = min(SEG_L, TN - start);      // 64, except tail (48)
    const bool exact  = (start <= SEG_W);            // s=0,1: replay from true init
    const int  wsteps = exact ? start : SEG_W;

    alignas(16) float w[16];
    const float* np_ = noise + (size_t)(start - wsteps) * B + b;

    if (exact) {
        // true initial state; s==0 also emits out[b, 0:16]
        const float4* i4 = (const float4*)(init + (size_t)b * 16);
        float4 a0 = i4[0], a1 = i4[1], a2 = i4[2], a3 = i4[3];
        w[0]  = a0.x; w[1]  = a0.y; w[2]  = a0.z; w[3]  = a0.w;
        w[4]  = a1.x; w[5]  = a1.y; w[6]  = a1.z; w[7]  = a1.w;
        w[8]  = a2.x; w[9]  = a2.y; w[10] = a2.z; w[11] = a2.w;
        w[12] = a3.x; w[13] = a3.y; w[14] = a3.z; w[15] = a3.w;
        if (s == 0) {
            float4* o4 = (float4*)(out + (size_t)b * T);
            o4[0] = a0; o4[1] = a1; o4[2] = a2; o4[3] = a3;
        }
    } else {
#pragma unroll
        for (int i = 0; i < 16; ++i) w[i] = 0.0f;
    }

    const int wch = wsteps >> 4;                     // warmup chunks (no store)
    const int nch = wch + (len >> 4);                // total chunks
    alignas(16) float buf[16];

    // prefetch chunk 0
#pragma unroll
    for (int k = 0; k < 16; ++k) buf[k] = np_[(size_t)k * B] * nstd;
    np_ += (size_t)16 * B;

    float* op = out + (size_t)b * T + 16 + start;

    for (int ch = 0; ch < nch - 1; ++ch) {
        // 16 steps; at step k, consume buf[k] then immediately prefetch the
        // next chunk's element into the same register. Loads for chunk ch+1
        // issue interleaved with chunk ch's FMAs -> counted vmcnt waits,
        // stores stay off the critical path.
#pragma unroll
        for (int k = 0; k < 16; ++k) {
            float e = buf[k];
            buf[k] = np_[(size_t)k * B] * nstd;
            w[k] = arstep(c, w, k, e);
        }
        np_ += (size_t)16 * B;
        if (ch >= wch) {                             // w[0..15] is chronological
#pragma unroll
            for (int q = 0; q < 4; ++q)
                __builtin_nontemporal_store(((const f32x4*)w)[q], (f32x4*)op + q);
            op += 16;
        }
    }

    // last chunk (always a store chunk; no prefetch)
#pragma unroll
    for (int k = 0; k < 16; ++k)
        w[k] = arstep(c, w, k, buf[k]);
#pragma unroll
    for (int q = 0; q < 4; ++q)
        __builtin_nontemporal_store(((const f32x4*)w)[q], (f32x4*)op + q);
}

extern "C" void kernel_launch(void* const* d_in, const int* in_sizes, int n_in,
                              void* d_out, int out_size, void* d_ws, size_t ws_size,
                              hipStream_t stream) {
    const float* init  = (const float*)d_in[0];   // (B,16)
    const float* coeff = (const float*)d_in[1];   // (16)
    const float* lns   = (const float*)d_in[2];   // (1)
    const float* noise = (const float*)d_in[3];   // (TN,B)
    float* out = (float*)d_out;                   // (B,T) fp32

    const int B   = in_sizes[0] / 16;             // 4096
    const int TN  = in_sizes[3] / B;              // 8176
    const int T   = TN + 16;                      // 8192
    const int S   = (TN + SEG_L - 1) / SEG_L;     // 128
    const int nbc = (B + 255) / 256;              // 16

    dim3 grid(nbc * S), block(256);               // 2048 blocks = 8 blocks/CU
    hipLaunchKernelGGL(ARModel_27925877359180_kernel, grid, block, 0, stream,
                       init, coeff, lns, noise, out, B, TN, T, nbc);
}

// Round 17
// 331.801 us; speedup vs baseline: 1.6324x; 1.6324x over previous
//
#include <hip/hip_runtime.h>

// AR(16) sequence generation, out (B=4096, T=8192) fp32.
// Time-segmented with zero-state warmup (contractive: |roots|>=1.1 => decay
// 0.909/step; 0.909^96 ~ 1e-4 << 0.48 threshold).
// R5 (13th submit; prior benches failed at GPU acquisition / container):
//   rolling prefetch (fixed) + REVERT non-temporal stores.
//   - R4 measured: 383 us, WRITE_SIZE 719 MB (4.3x amplification), FETCH 360 MB.
//     16B-granular __builtin_nontemporal_store defeats L2 write merging: each
//     64B lane-segment written back ~4x as partial lines + RMW fetches.
//     Cached stores (R3) measured 168 MB ~= ideal -> revert to plain stores.
//   - Rolling prefetch kept, with the nstd multiply moved to CONSUMPTION:
//     buf[] holds raw loads, so a load's first use is one chunk after issue
//     -> counted vmcnt(N) waits, 16 loads in flight behind compute.
//   - R3 baseline (no prefetch): 158 us, VALUBusy 20.6%, latency-bound on
//     per-chunk load drain.

#define SEG_L 64    // output-producing steps per segment
#define SEG_W 96    // max zero-state warmup steps (s>=2)

// Force a uniform value into an SGPR (frees a VGPR; v_fma takes 1 SGPR src).
__device__ __forceinline__ float sload(float v) {
    return __uint_as_float(__builtin_amdgcn_readfirstlane(__float_as_uint(v)));
}

// One recurrence step. Window invariant: at rotation k, y[t-16+i] == w[(k+i)&15].
// Dependent terms (i=14,15 -> produced 2 and 1 steps ago) applied LAST so the
// per-step critical path is ~2 FMA latencies; the rest is a 4-way tree.
__device__ __forceinline__ float arstep(const float (&c)[16], const float (&w)[16],
                                        int k, float e) {
    float p0 = fmaf(c[0],  w[(k + 0)  & 15], e);
    float p1 =      c[1] * w[(k + 1)  & 15];
    float p2 =      c[2] * w[(k + 2)  & 15];
    float p3 =      c[3] * w[(k + 3)  & 15];
    p0 = fmaf(c[4],  w[(k + 4)  & 15], p0);
    p1 = fmaf(c[5],  w[(k + 5)  & 15], p1);
    p2 = fmaf(c[6],  w[(k + 6)  & 15], p2);
    p3 = fmaf(c[7],  w[(k + 7)  & 15], p3);
    p0 = fmaf(c[8],  w[(k + 8)  & 15], p0);
    p1 = fmaf(c[9],  w[(k + 9)  & 15], p1);
    p2 = fmaf(c[10], w[(k + 10) & 15], p2);
    p3 = fmaf(c[11], w[(k + 11) & 15], p3);
    p0 = fmaf(c[12], w[(k + 12) & 15], p0);
    p1 = fmaf(c[13], w[(k + 13) & 15], p1);
    p0 += p2;
    p1 += p3;
    p0 += p1;
    p0 = fmaf(c[14], w[(k + 14) & 15], p0);   // critical-path tail
    return fmaf(c[15], w[(k + 15) & 15], p0); // newest value last
}

__global__ __launch_bounds__(256, 8)   // 8 waves/EU => <=64 VGPR => 32 waves/CU
void ARModel_27925877359180_kernel(const float* __restrict__ init,   // (B,16)
                                   const float* __restrict__ coeff,  // (16)
                                   const float* __restrict__ lns,    // (1)
                                   const float* __restrict__ noise,  // (TN,B)
                                   float* __restrict__ out,          // (B,T)
                                   int B, int TN, int T, int nbc)
{
    const int blk = blockIdx.x;
    const int s   = blk / nbc;                       // segment index
    const int b   = (blk % nbc) * blockDim.x + threadIdx.x;
    if (b >= B) return;

    float c[16];
#pragma unroll
    for (int i = 0; i < 16; ++i) c[i] = sload(coeff[i]);
    const float nstd = sload(expf(lns[0]));

    const int  start  = s * SEG_L;                   // first main noise index
    const int  len    = min(SEG_L, TN - start);      // 64, except tail (48)
    const bool exact  = (start <= SEG_W);            // s=0,1: replay from true init
    const int  wsteps = exact ? start : SEG_W;

    alignas(16) float w[16];
    const float* np_ = noise + (size_t)(start - wsteps) * B + b;

    if (exact) {
        // true initial state; s==0 also emits out[b, 0:16]
        const float4* i4 = (const float4*)(init + (size_t)b * 16);
        float4 a0 = i4[0], a1 = i4[1], a2 = i4[2], a3 = i4[3];
        w[0]  = a0.x; w[1]  = a0.y; w[2]  = a0.z; w[3]  = a0.w;
        w[4]  = a1.x; w[5]  = a1.y; w[6]  = a1.z; w[7]  = a1.w;
        w[8]  = a2.x; w[9]  = a2.y; w[10] = a2.z; w[11] = a2.w;
        w[12] = a3.x; w[13] = a3.y; w[14] = a3.z; w[15] = a3.w;
        if (s == 0) {
            float4* o4 = (float4*)(out + (size_t)b * T);
            o4[0] = a0; o4[1] = a1; o4[2] = a2; o4[3] = a3;
        }
    } else {
#pragma unroll
        for (int i = 0; i < 16; ++i) w[i] = 0.0f;
    }

    const int wch = wsteps >> 4;                     // warmup chunks (no store)
    const int nch = wch + (len >> 4);                // total chunks
    float buf[16];                                   // RAW noise (nstd applied at use)

    // prefetch chunk 0
#pragma unroll
    for (int k = 0; k < 16; ++k) buf[k] = np_[(size_t)k * B];
    np_ += (size_t)16 * B;

    float* op = out + (size_t)b * T + 16 + start;

    for (int ch = 0; ch < nch - 1; ++ch) {
        // At step k: consume buf[k] (its load completed ~1 chunk ago), then
        // immediately issue next chunk's load into the same register. First
        // use of each load is one full chunk after issue -> counted vmcnt,
        // 16 loads in flight behind the 256 FMAs.
#pragma unroll
        for (int k = 0; k < 16; ++k) {
            float e = buf[k] * nstd;
            buf[k] = np_[(size_t)k * B];
            w[k] = arstep(c, w, k, e);
        }
        np_ += (size_t)16 * B;
        if (ch >= wch) {                             // w[0..15] is chronological
            float4* o4 = (float4*)op;
#pragma unroll
            for (int q = 0; q < 4; ++q) o4[q] = ((const float4*)w)[q];
            op += 16;
        }
    }

    // last chunk (always a store chunk; no prefetch)
#pragma unroll
    for (int k = 0; k < 16; ++k)
        w[k] = arstep(c, w, k, buf[k] * nstd);
    float4* o4 = (float4*)op;
#pragma unroll
    for (int q = 0; q < 4; ++q) o4[q] = ((const float4*)w)[q];
}

extern "C" void kernel_launch(void* const* d_in, const int* in_sizes, int n_in,
                              void* d_out, int out_size, void* d_ws, size_t ws_size,
                              hipStream_t stream) {
    const float* init  = (const float*)d_in[0];   // (B,16)
    const float* coeff = (const float*)d_in[1];   // (16)
    const float* lns   = (const float*)d_in[2];   // (1)
    const float* noise = (const float*)d_in[3];   // (TN,B)
    float* out = (float*)d_out;                   // (B,T) fp32

    const int B   = in_sizes[0] / 16;             // 4096
    const int TN  = in_sizes[3] / B;              // 8176
    const int T   = TN + 16;                      // 8192
    const int S   = (TN + SEG_L - 1) / SEG_L;     // 128
    const int nbc = (B + 255) / 256;              // 16

    dim3 grid(nbc * S), block(256);               // 2048 blocks = 8 blocks/CU
    hipLaunchKernelGGL(ARModel_27925877359180_kernel, grid, block, 0, stream,
                       init, coeff, lns, noise, out, B, TN, T, nbc);
}